// Round 1
// baseline (1401.509 us; speedup 1.0000x reference)
//
#include <hip/hip_runtime.h>
#include <math.h>

#define LTOK 2304
#define CDIM 768
#define NHEAD 12
#define HDIM 64
#define HS 48

static constexpr float ATT_SCALE = 0.125f;  // 64^-0.5

// ---------------- LayerNorm: one block per row (C=768, 256 threads) ----------------
__global__ __launch_bounds__(256) void ln_kernel(const float* __restrict__ x,
                                                 const float* __restrict__ w,
                                                 const float* __restrict__ b,
                                                 float* __restrict__ out) {
  const int row = blockIdx.x;
  const int t = threadIdx.x;
  const float* xr = x + (size_t)row * CDIM;
  float v0 = xr[t], v1 = xr[t + 256], v2 = xr[t + 512];
  float s = v0 + v1 + v2;
  float ss = v0 * v0 + v1 * v1 + v2 * v2;
#pragma unroll
  for (int off = 32; off > 0; off >>= 1) {
    s += __shfl_down(s, off, 64);
    ss += __shfl_down(ss, off, 64);
  }
  __shared__ float rs[4], rss[4];
  if ((t & 63) == 0) { rs[t >> 6] = s; rss[t >> 6] = ss; }
  __syncthreads();
  float S = rs[0] + rs[1] + rs[2] + rs[3];
  float SS = rss[0] + rss[1] + rss[2] + rss[3];
  const float inv_c = 1.0f / (float)CDIM;
  float mu = S * inv_c;
  float var = SS * inv_c - mu * mu;
  float inv = rsqrtf(var + 1e-5f);
  float* orow = out + (size_t)row * CDIM;
  orow[t]       = (v0 - mu) * inv * w[t]       + b[t];
  orow[t + 256] = (v1 - mu) * inv * w[t + 256] + b[t + 256];
  orow[t + 512] = (v2 - mu) * inv * w[t + 512] + b[t + 512];
}

// ---------------- GEMM: C[M,N] = A[M,K] @ B[N,K]^T + bias (+GELU) (+residual) -------
// Tiles: BM=BN=128, BK=8. 256 threads, 8x8 microtile per thread.
// Requires M%128==0, N%128==0, K%8==0 (true for all uses here).
template <bool GELU, bool RES>
__global__ __launch_bounds__(256) void gemm_kernel(const float* __restrict__ A,
                                                   const float* __restrict__ B,
                                                   const float* __restrict__ bias,
                                                   const float* __restrict__ res,
                                                   float* __restrict__ C,
                                                   int M, int N, int K) {
  __shared__ float As[8][128];  // [k][m]
  __shared__ float Bs[8][128];  // [k][n]
  const int t = threadIdx.x;
  const int tx = t & 15;        // n-group
  const int ty = t >> 4;        // m-group
  const int bm = blockIdx.y * 128;
  const int bn = blockIdx.x * 128;
  const int ra = t >> 1;        // 0..127 row within tile
  const int kc = (t & 1) * 4;   // 0 or 4

  float acc[8][8];
#pragma unroll
  for (int i = 0; i < 8; ++i)
#pragma unroll
    for (int j = 0; j < 8; ++j) acc[i][j] = 0.f;

  const float* Ap = A + (size_t)(bm + ra) * K + kc;
  const float* Bp = B + (size_t)(bn + ra) * K + kc;

  float4 av = *(const float4*)(Ap);
  float4 bv = *(const float4*)(Bp);

  for (int k0 = 0; k0 < K; k0 += 8) {
    __syncthreads();
    As[kc + 0][ra] = av.x; As[kc + 1][ra] = av.y; As[kc + 2][ra] = av.z; As[kc + 3][ra] = av.w;
    Bs[kc + 0][ra] = bv.x; Bs[kc + 1][ra] = bv.y; Bs[kc + 2][ra] = bv.z; Bs[kc + 3][ra] = bv.w;
    __syncthreads();
    if (k0 + 8 < K) {
      av = *(const float4*)(Ap + k0 + 8);
      bv = *(const float4*)(Bp + k0 + 8);
    }
#pragma unroll
    for (int kk = 0; kk < 8; ++kk) {
      float4 a0 = *(const float4*)&As[kk][ty * 8];
      float4 a1 = *(const float4*)&As[kk][ty * 8 + 4];
      float4 b0 = *(const float4*)&Bs[kk][tx * 8];
      float4 b1 = *(const float4*)&Bs[kk][tx * 8 + 4];
      float a[8] = {a0.x, a0.y, a0.z, a0.w, a1.x, a1.y, a1.z, a1.w};
      float b[8] = {b0.x, b0.y, b0.z, b0.w, b1.x, b1.y, b1.z, b1.w};
#pragma unroll
      for (int i = 0; i < 8; ++i)
#pragma unroll
        for (int j = 0; j < 8; ++j) acc[i][j] += a[i] * b[j];
    }
  }

#pragma unroll
  for (int i = 0; i < 8; ++i) {
    const int m = bm + ty * 8 + i;
#pragma unroll
    for (int j = 0; j < 8; ++j) {
      const int n = bn + tx * 8 + j;
      float v = acc[i][j] + bias[n];
      if (GELU) v = 0.5f * v * (1.0f + erff(v * 0.70710678118654752f));
      if (RES) v += res[(size_t)m * N + n];
      C[(size_t)m * N + n] = v;
    }
  }
}

// ---------------- RoPE cos/sin tables: [L][32] ----------------
__global__ __launch_bounds__(256) void rope_cs_kernel(float* __restrict__ cs,
                                                      float* __restrict__ sn) {
  const int idx = blockIdx.x * 256 + threadIdx.x;  // < 2304*32
  const int l = idx >> 5;
  const int i = idx & 31;
  const int j = i & 15;
  // f = 10000^(-j/16) = exp(-j * ln(10000)/16)
  const float f = __expf(-(float)j * 0.57564627324851142f);
  const float coord = (i < 16) ? (float)(l % HS) : (float)(l / HS);
  const float ang = coord * f;
  cs[idx] = cosf(ang);
  sn[idx] = sinf(ang);
}

// ---------------- RoPE apply (in-place on q,k parts of qkv [L][3C]) ----------------
__global__ __launch_bounds__(256) void rope_apply_kernel(float* __restrict__ qkv,
                                                         const float* __restrict__ cs,
                                                         const float* __restrict__ sn) {
  const int idx = blockIdx.x * 256 + threadIdx.x;  // < 2304*2*12*32
  const int i = idx & 31;
  int rest = idx >> 5;           // l*24 + p*12 + n
  const int n = rest % 12;
  rest /= 12;
  const int p = rest & 1;
  const int l = rest >> 1;
  float* base = qkv + (size_t)l * (3 * CDIM) + p * CDIM + n * HDIM + 2 * i;
  const float re = base[0], im = base[1];
  const float c = cs[l * 32 + i], s = sn[l * 32 + i];
  base[0] = re * c - im * s;
  base[1] = re * s + im * c;
}

// ---------------- Attention: flash-style, per (head, 32-row q tile) ----------------
// grid = (72, 12), block = 256
__global__ __launch_bounds__(256) void attn_kernel(const float* __restrict__ qkv,
                                                   const float* __restrict__ relh,
                                                   const float* __restrict__ relw,
                                                   float* __restrict__ out) {
  __shared__ float q_s[32][65];   // padded: conflict-free row-scalar reads
  __shared__ float K_s[64][64];   // transposed: [d][kj]
  __shared__ float V_s[64][64];   // natural:    [kj][d]
  __shared__ float p_s[32][68];   // scores then probs
  __shared__ float bh[32][48];
  __shared__ float bw[32][48];
  __shared__ float psum[32][16];
  __shared__ float m_s[32], l_s[32], al_s[32];

  const int t = threadIdx.x;
  const int n = blockIdx.y;
  const int l0 = blockIdx.x * 32;
  const float* Qg = qkv + n * HDIM;
  const float* Kg = qkv + CDIM + n * HDIM;
  const float* Vg = qkv + 2 * CDIM + n * HDIM;

  // stage q tile: 32x64
#pragma unroll
  for (int r = 0; r < 8; ++r) {
    const int idx = t + r * 256;
    const int row = idx >> 6, d = idx & 63;
    q_s[row][d] = Qg[(size_t)(l0 + row) * (3 * CDIM) + d];
  }
  if (t < 32) { m_s[t] = -3e38f; l_s[t] = 0.f; }
  __syncthreads();

  // rel-pos bias: bh[row][kh], bw[row][kw] (3072 dot-64s, 12 per thread)
  for (int dI = t; dI < 3072; dI += 256) {
    const int isW = dI >= 1536;
    const int rem = isW ? dI - 1536 : dI;
    const int row = rem / 48, col = rem % 48;
    const int l = l0 + row;
    const int qc = isW ? (l % HS) : (l / HS);
    const float* rel = (isW ? relw : relh) + (size_t)(qc - col + HS - 1) * HDIM;
    float acc = 0.f;
#pragma unroll
    for (int d = 0; d < 64; ++d) acc += q_s[row][d] * rel[d];
    if (isW) bw[row][col] = acc; else bh[row][col] = acc;
  }

  float4 o0 = {0, 0, 0, 0}, o1 = {0, 0, 0, 0};
  const int g = t >> 4;     // row pair: rows 2g, 2g+1
  const int kjg = t & 15;   // key group (s-phase) / d group (V-phase)

  for (int kt = 0; kt < 36; ++kt) {
    const int l2b = kt * 64;
    __syncthreads();  // previous tile fully consumed (also covers bias/q on kt=0)
    // stage K (transposed) + V (natural)
#pragma unroll
    for (int r = 0; r < 4; ++r) {
      const int idx = t + r * 256;
      const int kj = idx & 63, c4 = (idx >> 6) * 4;
      const float4 kv = *(const float4*)&Kg[(size_t)(l2b + kj) * (3 * CDIM) + c4];
      K_s[c4 + 0][kj] = kv.x; K_s[c4 + 1][kj] = kv.y;
      K_s[c4 + 2][kj] = kv.z; K_s[c4 + 3][kj] = kv.w;
      const int kj2 = idx >> 4, d4 = (idx & 15) * 4;
      *(float4*)&V_s[kj2][d4] = *(const float4*)&Vg[(size_t)(l2b + kj2) * (3 * CDIM) + d4];
    }
    __syncthreads();

    // s-phase: 2 rows x 4 keys per thread
    float4 s0 = {0, 0, 0, 0}, s1 = {0, 0, 0, 0};
#pragma unroll 8
    for (int d = 0; d < 64; ++d) {
      const float4 k4 = *(const float4*)&K_s[d][kjg * 4];
      const float qa = q_s[2 * g][d], qb = q_s[2 * g + 1][d];
      s0.x += qa * k4.x; s0.y += qa * k4.y; s0.z += qa * k4.z; s0.w += qa * k4.w;
      s1.x += qb * k4.x; s1.y += qb * k4.y; s1.z += qb * k4.z; s1.w += qb * k4.w;
    }
    float4 sb0, sb1;
    {
      const int l2 = l2b + kjg * 4;
      const int kh0 = l2 / 48, kw0 = l2 - kh0 * 48;
      const int kh1 = (l2 + 1) / 48, kw1 = (l2 + 1) - kh1 * 48;
      const int kh2 = (l2 + 2) / 48, kw2 = (l2 + 2) - kh2 * 48;
      const int kh3 = (l2 + 3) / 48, kw3 = (l2 + 3) - kh3 * 48;
      sb0.x = s0.x * ATT_SCALE + bh[2 * g][kh0] + bw[2 * g][kw0];
      sb0.y = s0.y * ATT_SCALE + bh[2 * g][kh1] + bw[2 * g][kw1];
      sb0.z = s0.z * ATT_SCALE + bh[2 * g][kh2] + bw[2 * g][kw2];
      sb0.w = s0.w * ATT_SCALE + bh[2 * g][kh3] + bw[2 * g][kw3];
      sb1.x = s1.x * ATT_SCALE + bh[2 * g + 1][kh0] + bw[2 * g + 1][kw0];
      sb1.y = s1.y * ATT_SCALE + bh[2 * g + 1][kh1] + bw[2 * g + 1][kw1];
      sb1.z = s1.z * ATT_SCALE + bh[2 * g + 1][kh2] + bw[2 * g + 1][kw2];
      sb1.w = s1.w * ATT_SCALE + bh[2 * g + 1][kh3] + bw[2 * g + 1][kw3];
      *(float4*)&p_s[2 * g][kjg * 4] = sb0;
      *(float4*)&p_s[2 * g + 1][kjg * 4] = sb1;
    }
    __syncthreads();

    // row stats
    if (t < 32) {
      const float mo = m_s[t];
      float mn = mo;
#pragma unroll 8
      for (int kj = 0; kj < 64; ++kj) mn = fmaxf(mn, p_s[t][kj]);
      m_s[t] = mn;
      al_s[t] = __expf(mo - mn);
    }
    __syncthreads();

    // convert to probs + partial sums + rescale accumulators
    {
      const float mn0 = m_s[2 * g], mn1 = m_s[2 * g + 1];
      float4 pv0, pv1;
      pv0.x = __expf(sb0.x - mn0); pv0.y = __expf(sb0.y - mn0);
      pv0.z = __expf(sb0.z - mn0); pv0.w = __expf(sb0.w - mn0);
      pv1.x = __expf(sb1.x - mn1); pv1.y = __expf(sb1.y - mn1);
      pv1.z = __expf(sb1.z - mn1); pv1.w = __expf(sb1.w - mn1);
      *(float4*)&p_s[2 * g][kjg * 4] = pv0;
      *(float4*)&p_s[2 * g + 1][kjg * 4] = pv1;
      psum[2 * g][kjg] = pv0.x + pv0.y + pv0.z + pv0.w;
      psum[2 * g + 1][kjg] = pv1.x + pv1.y + pv1.z + pv1.w;
      const float a0 = al_s[2 * g], a1 = al_s[2 * g + 1];
      o0.x *= a0; o0.y *= a0; o0.z *= a0; o0.w *= a0;
      o1.x *= a1; o1.y *= a1; o1.z *= a1; o1.w *= a1;
    }
    __syncthreads();
    if (t < 32) {
      float ssum = 0.f;
#pragma unroll
      for (int j = 0; j < 16; ++j) ssum += psum[t][j];
      l_s[t] = l_s[t] * al_s[t] + ssum;
    }
    // V accumulation: rows 2g,2g+1, dims kjg*4..+3
#pragma unroll 8
    for (int kj = 0; kj < 64; ++kj) {
      const float4 v4 = *(const float4*)&V_s[kj][kjg * 4];
      const float pa = p_s[2 * g][kj], pb = p_s[2 * g + 1][kj];
      o0.x += pa * v4.x; o0.y += pa * v4.y; o0.z += pa * v4.z; o0.w += pa * v4.w;
      o1.x += pb * v4.x; o1.y += pb * v4.y; o1.z += pb * v4.z; o1.w += pb * v4.w;
    }
  }
  __syncthreads();
  {
    const float inv0 = 1.f / l_s[2 * g];
    const float inv1 = 1.f / l_s[2 * g + 1];
    float4 r0 = {o0.x * inv0, o0.y * inv0, o0.z * inv0, o0.w * inv0};
    float4 r1 = {o1.x * inv1, o1.y * inv1, o1.z * inv1, o1.w * inv1};
    *(float4*)&out[(size_t)(l0 + 2 * g) * CDIM + n * HDIM + kjg * 4] = r0;
    *(float4*)&out[(size_t)(l0 + 2 * g + 1) * CDIM + n * HDIM + kjg * 4] = r1;
  }
}

// ---------------- launch ----------------
extern "C" void kernel_launch(void* const* d_in, const int* in_sizes, int n_in,
                              void* d_out, int out_size, void* d_ws, size_t ws_size,
                              hipStream_t stream) {
  const float* x     = (const float*)d_in[0];
  const float* ln1w  = (const float*)d_in[1];
  const float* ln1b  = (const float*)d_in[2];
  const float* qkvw  = (const float*)d_in[3];
  const float* qkvb  = (const float*)d_in[4];
  const float* relh  = (const float*)d_in[5];
  const float* relw  = (const float*)d_in[6];
  const float* projw = (const float*)d_in[7];
  const float* projb = (const float*)d_in[8];
  const float* ln2w  = (const float*)d_in[9];
  const float* ln2b  = (const float*)d_in[10];
  const float* fc1w  = (const float*)d_in[11];
  const float* fc1b  = (const float*)d_in[12];
  const float* fc2w  = (const float*)d_in[13];
  const float* fc2b  = (const float*)d_in[14];
  float* out = (float*)d_out;
  float* ws = (float*)d_ws;

  float* h      = ws;                                  // L*C
  float* x1     = h + (size_t)LTOK * CDIM;             // L*C
  float* attn_o = x1 + (size_t)LTOK * CDIM;            // L*C
  float* cs     = attn_o + (size_t)LTOK * CDIM;        // L*32
  float* sn     = cs + (size_t)LTOK * 32;              // L*32
  float* big    = sn + (size_t)LTOK * 32;              // L*4C (qkv then mlp-hidden)

  // 1. LN1
  ln_kernel<<<LTOK, 256, 0, stream>>>(x, ln1w, ln1b, h);
  // 2. qkv = h @ qkv_w^T + b   [2304, 2304]
  gemm_kernel<false, false><<<dim3(18, 18), 256, 0, stream>>>(h, qkvw, qkvb, nullptr, big,
                                                              LTOK, 3 * CDIM, CDIM);
  // 3. RoPE tables + apply to q,k
  rope_cs_kernel<<<288, 256, 0, stream>>>(cs, sn);
  rope_apply_kernel<<<6912, 256, 0, stream>>>(big, cs, sn);
  // 4. attention (with decomposed rel-pos bias)
  attn_kernel<<<dim3(72, 12), 256, 0, stream>>>(big, relh, relw, attn_o);
  // 5. x1 = x + attn_o @ proj_w^T + b
  gemm_kernel<false, true><<<dim3(6, 18), 256, 0, stream>>>(attn_o, projw, projb, x, x1,
                                                            LTOK, CDIM, CDIM);
  // 6. LN2
  ln_kernel<<<LTOK, 256, 0, stream>>>(x1, ln2w, ln2b, h);
  // 7. m1 = gelu(h @ fc1_w^T + b)   [2304, 3072]
  gemm_kernel<true, false><<<dim3(24, 18), 256, 0, stream>>>(h, fc1w, fc1b, nullptr, big,
                                                             LTOK, 4 * CDIM, CDIM);
  // 8. out = x1 + m1 @ fc2_w^T + b
  gemm_kernel<false, true><<<dim3(6, 18), 256, 0, stream>>>(big, fc2w, fc2b, x1, out,
                                                            LTOK, CDIM, 4 * CDIM);
}

// Round 2
// 819.802 us; speedup vs baseline: 1.7096x; 1.7096x over previous
//
#include <hip/hip_runtime.h>
#include <math.h>

#define LTOK 2304
#define CDIM 768
#define NHEAD 12
#define HDIM 64
#define HS 48

static constexpr float ATT_SCALE = 0.125f;  // 64^-0.5

typedef short s16x8 __attribute__((ext_vector_type(8)));   // 8 bf16 bits (4 VGPRs)
typedef float f32x4 __attribute__((ext_vector_type(4)));

__device__ __forceinline__ unsigned short f2b(float f) {
  __bf16 b = (__bf16)f;   // RNE
  return __builtin_bit_cast(unsigned short, b);
}

__device__ __forceinline__ void gld_lds16(void* lds, const void* g) {
  __builtin_amdgcn_global_load_lds(
      (const __attribute__((address_space(1))) unsigned int*)g,
      (__attribute__((address_space(3))) unsigned int*)lds, 16, 0, 0);
}

// ---------------- fp32 -> bf16 convert (n % 8 == 0) ----------------
__global__ __launch_bounds__(256) void f2b_kernel(const float* __restrict__ in,
                                                  unsigned short* __restrict__ out, int n) {
  const int i = (blockIdx.x * 256 + threadIdx.x) * 8;
  if (i + 8 > n) return;
  float4 v0 = *(const float4*)(in + i);
  float4 v1 = *(const float4*)(in + i + 4);
  unsigned short o[8] = {f2b(v0.x), f2b(v0.y), f2b(v0.z), f2b(v0.w),
                         f2b(v1.x), f2b(v1.y), f2b(v1.z), f2b(v1.w)};
  *(uint4*)(out + i) = *(const uint4*)o;
}

// ---------------- LayerNorm: fp32 in, bf16 out ----------------
__global__ __launch_bounds__(256) void ln_kernel(const float* __restrict__ x,
                                                 const float* __restrict__ w,
                                                 const float* __restrict__ b,
                                                 unsigned short* __restrict__ out) {
  const int row = blockIdx.x;
  const int t = threadIdx.x;
  const float* xr = x + (size_t)row * CDIM;
  float v0 = xr[t], v1 = xr[t + 256], v2 = xr[t + 512];
  float s = v0 + v1 + v2;
  float ss = v0 * v0 + v1 * v1 + v2 * v2;
#pragma unroll
  for (int off = 32; off > 0; off >>= 1) {
    s += __shfl_down(s, off, 64);
    ss += __shfl_down(ss, off, 64);
  }
  __shared__ float rs[4], rss[4];
  if ((t & 63) == 0) { rs[t >> 6] = s; rss[t >> 6] = ss; }
  __syncthreads();
  float S = rs[0] + rs[1] + rs[2] + rs[3];
  float SS = rss[0] + rss[1] + rss[2] + rss[3];
  const float inv_c = 1.0f / (float)CDIM;
  float mu = S * inv_c;
  float var = SS * inv_c - mu * mu;
  float inv = rsqrtf(var + 1e-5f);
  unsigned short* orow = out + (size_t)row * CDIM;
  orow[t]       = f2b((v0 - mu) * inv * w[t]       + b[t]);
  orow[t + 256] = f2b((v1 - mu) * inv * w[t + 256] + b[t + 256]);
  orow[t + 512] = f2b((v2 - mu) * inv * w[t + 512] + b[t + 512]);
}

// ---------------- bf16 MFMA GEMM (m97 structure) ----------------
// C[M,N] = A[M,K](bf16) @ B[N,K](bf16)^T + bias, optional GELU / +res, out fp32 or bf16.
// BM=BN=128, BK=32, 256 threads = 4 waves (2x2), each wave 64x64 = 4x4 16x16 frags.
template <bool GELU, bool RES, bool OUTBF>
__global__ __launch_bounds__(256) void mfma_gemm(const unsigned short* __restrict__ A,
                                                 const unsigned short* __restrict__ B,
                                                 const float* __restrict__ bias,
                                                 const float* __restrict__ res,
                                                 void* __restrict__ Cout,
                                                 int M, int N, int K) {
  __shared__ unsigned short As[128 * 32];
  __shared__ unsigned short Bs[128 * 32];
  const int t = threadIdx.x;
  const int lane = t & 63;
  const int w = t >> 6;
  const int wm = w >> 1, wn = w & 1;
  const int bm = blockIdx.y * 128, bn = blockIdx.x * 128;

  f32x4 acc[4][4] = {};

  // staging: wave w stages 1KB chunks {2w, 2w+1} of each tile.
  // chunk c covers tile rows 16c..16c+15 (rows of 32 bf16 = 64B).
  // lane i -> row 16c + i/4, k-offset (i%4)*8 elems (16B).
  const int c0 = 2 * w, c1 = 2 * w + 1;
  const int srow = lane >> 2;
  const int skof = (lane & 3) * 8;
  const unsigned short* Abase = A + (size_t)bm * K + skof;
  const unsigned short* Bbase = B + (size_t)bn * K + skof;
  const int lr = lane & 15, lk = (lane >> 4) * 8, lg = lane >> 4;

  for (int k0 = 0; k0 < K; k0 += 32) {
    gld_lds16(As + c0 * 512, Abase + (size_t)(c0 * 16 + srow) * K + k0);
    gld_lds16(As + c1 * 512, Abase + (size_t)(c1 * 16 + srow) * K + k0);
    gld_lds16(Bs + c0 * 512, Bbase + (size_t)(c0 * 16 + srow) * K + k0);
    gld_lds16(Bs + c1 * 512, Bbase + (size_t)(c1 * 16 + srow) * K + k0);
    __syncthreads();   // compiler inserts vmcnt(0) drain
    s16x8 a[4], b[4];
#pragma unroll
    for (int m = 0; m < 4; ++m)
      a[m] = *(const s16x8*)&As[(wm * 64 + m * 16 + lr) * 32 + lk];
#pragma unroll
    for (int n = 0; n < 4; ++n)
      b[n] = *(const s16x8*)&Bs[(wn * 64 + n * 16 + lr) * 32 + lk];
#pragma unroll
    for (int m = 0; m < 4; ++m)
#pragma unroll
      for (int n = 0; n < 4; ++n)
        acc[m][n] = __builtin_amdgcn_mfma_f32_16x16x32_bf16(a[m], b[n], acc[m][n], 0, 0, 0);
    __syncthreads();   // LDS fully consumed before next stage
  }

  // epilogue: C/D layout col=lane&15, row=(lane>>4)*4+reg
#pragma unroll
  for (int n = 0; n < 4; ++n) {
    const int col = bn + wn * 64 + n * 16 + lr;
    const float bc = bias[col];
#pragma unroll
    for (int m = 0; m < 4; ++m) {
#pragma unroll
      for (int j = 0; j < 4; ++j) {
        const int row = bm + wm * 64 + m * 16 + lg * 4 + j;
        float v = acc[m][n][j] + bc;
        if (GELU) v = 0.5f * v * (1.0f + erff(v * 0.70710678118654752f));
        if (RES) v += res[(size_t)row * N + col];
        if (OUTBF) ((unsigned short*)Cout)[(size_t)row * N + col] = f2b(v);
        else       ((float*)Cout)[(size_t)row * N + col] = v;
      }
    }
  }
}

// ---------------- RoPE cos/sin tables: [L][32] ----------------
__global__ __launch_bounds__(256) void rope_cs_kernel(float* __restrict__ cs,
                                                      float* __restrict__ sn) {
  const int idx = blockIdx.x * 256 + threadIdx.x;  // < 2304*32
  const int l = idx >> 5;
  const int i = idx & 31;
  const int j = i & 15;
  const float f = __expf(-(float)j * 0.57564627324851142f);
  const float coord = (i < 16) ? (float)(l % HS) : (float)(l / HS);
  const float ang = coord * f;
  cs[idx] = cosf(ang);
  sn[idx] = sinf(ang);
}

// ---------------- RoPE apply (in-place on fp32 qkv [L][3C]) ----------------
__global__ __launch_bounds__(256) void rope_apply_kernel(float* __restrict__ qkv,
                                                         const float* __restrict__ cs,
                                                         const float* __restrict__ sn) {
  const int idx = blockIdx.x * 256 + threadIdx.x;  // < 2304*2*12*32
  const int i = idx & 31;
  int rest = idx >> 5;           // l*24 + p*12 + n
  const int n = rest % 12;
  rest /= 12;
  const int p = rest & 1;
  const int l = rest >> 1;
  float* base = qkv + (size_t)l * (3 * CDIM) + p * CDIM + n * HDIM + 2 * i;
  const float re = base[0], im = base[1];
  const float c = cs[l * 32 + i], s = sn[l * 32 + i];
  base[0] = re * c - im * s;
  base[1] = re * s + im * c;
}

// ---------------- Attention: flash-style fp32 (unchanged; bf16 output) ----------------
// grid = (72, 12), block = 256
__global__ __launch_bounds__(256) void attn_kernel(const float* __restrict__ qkv,
                                                   const float* __restrict__ relh,
                                                   const float* __restrict__ relw,
                                                   unsigned short* __restrict__ out) {
  __shared__ float q_s[32][65];
  __shared__ float K_s[64][64];   // transposed: [d][kj]
  __shared__ float V_s[64][64];   // natural:    [kj][d]
  __shared__ float p_s[32][68];
  __shared__ float bh[32][48];
  __shared__ float bw[32][48];
  __shared__ float psum[32][16];
  __shared__ float m_s[32], l_s[32], al_s[32];

  const int t = threadIdx.x;
  const int n = blockIdx.y;
  const int l0 = blockIdx.x * 32;
  const float* Qg = qkv + n * HDIM;
  const float* Kg = qkv + CDIM + n * HDIM;
  const float* Vg = qkv + 2 * CDIM + n * HDIM;

#pragma unroll
  for (int r = 0; r < 8; ++r) {
    const int idx = t + r * 256;
    const int row = idx >> 6, d = idx & 63;
    q_s[row][d] = Qg[(size_t)(l0 + row) * (3 * CDIM) + d];
  }
  if (t < 32) { m_s[t] = -3e38f; l_s[t] = 0.f; }
  __syncthreads();

  for (int dI = t; dI < 3072; dI += 256) {
    const int isW = dI >= 1536;
    const int rem = isW ? dI - 1536 : dI;
    const int row = rem / 48, col = rem % 48;
    const int l = l0 + row;
    const int qc = isW ? (l % HS) : (l / HS);
    const float* rel = (isW ? relw : relh) + (size_t)(qc - col + HS - 1) * HDIM;
    float acc = 0.f;
#pragma unroll
    for (int d = 0; d < 64; ++d) acc += q_s[row][d] * rel[d];
    if (isW) bw[row][col] = acc; else bh[row][col] = acc;
  }

  float4 o0 = {0, 0, 0, 0}, o1 = {0, 0, 0, 0};
  const int g = t >> 4;
  const int kjg = t & 15;

  for (int kt = 0; kt < 36; ++kt) {
    const int l2b = kt * 64;
    __syncthreads();
#pragma unroll
    for (int r = 0; r < 4; ++r) {
      const int idx = t + r * 256;
      const int kj = idx & 63, c4 = (idx >> 6) * 4;
      const float4 kv = *(const float4*)&Kg[(size_t)(l2b + kj) * (3 * CDIM) + c4];
      K_s[c4 + 0][kj] = kv.x; K_s[c4 + 1][kj] = kv.y;
      K_s[c4 + 2][kj] = kv.z; K_s[c4 + 3][kj] = kv.w;
      const int kj2 = idx >> 4, d4 = (idx & 15) * 4;
      *(float4*)&V_s[kj2][d4] = *(const float4*)&Vg[(size_t)(l2b + kj2) * (3 * CDIM) + d4];
    }
    __syncthreads();

    float4 s0 = {0, 0, 0, 0}, s1 = {0, 0, 0, 0};
#pragma unroll 8
    for (int d = 0; d < 64; ++d) {
      const float4 k4 = *(const float4*)&K_s[d][kjg * 4];
      const float qa = q_s[2 * g][d], qb = q_s[2 * g + 1][d];
      s0.x += qa * k4.x; s0.y += qa * k4.y; s0.z += qa * k4.z; s0.w += qa * k4.w;
      s1.x += qb * k4.x; s1.y += qb * k4.y; s1.z += qb * k4.z; s1.w += qb * k4.w;
    }
    float4 sb0, sb1;
    {
      const int l2 = l2b + kjg * 4;
      const int kh0 = l2 / 48, kw0 = l2 - kh0 * 48;
      const int kh1 = (l2 + 1) / 48, kw1 = (l2 + 1) - kh1 * 48;
      const int kh2 = (l2 + 2) / 48, kw2 = (l2 + 2) - kh2 * 48;
      const int kh3 = (l2 + 3) / 48, kw3 = (l2 + 3) - kh3 * 48;
      sb0.x = s0.x * ATT_SCALE + bh[2 * g][kh0] + bw[2 * g][kw0];
      sb0.y = s0.y * ATT_SCALE + bh[2 * g][kh1] + bw[2 * g][kw1];
      sb0.z = s0.z * ATT_SCALE + bh[2 * g][kh2] + bw[2 * g][kw2];
      sb0.w = s0.w * ATT_SCALE + bh[2 * g][kh3] + bw[2 * g][kw3];
      sb1.x = s1.x * ATT_SCALE + bh[2 * g + 1][kh0] + bw[2 * g + 1][kw0];
      sb1.y = s1.y * ATT_SCALE + bh[2 * g + 1][kh1] + bw[2 * g + 1][kw1];
      sb1.z = s1.z * ATT_SCALE + bh[2 * g + 1][kh2] + bw[2 * g + 1][kw2];
      sb1.w = s1.w * ATT_SCALE + bh[2 * g + 1][kh3] + bw[2 * g + 1][kw3];
      *(float4*)&p_s[2 * g][kjg * 4] = sb0;
      *(float4*)&p_s[2 * g + 1][kjg * 4] = sb1;
    }
    __syncthreads();

    if (t < 32) {
      const float mo = m_s[t];
      float mn = mo;
#pragma unroll 8
      for (int kj = 0; kj < 64; ++kj) mn = fmaxf(mn, p_s[t][kj]);
      m_s[t] = mn;
      al_s[t] = __expf(mo - mn);
    }
    __syncthreads();

    {
      const float mn0 = m_s[2 * g], mn1 = m_s[2 * g + 1];
      float4 pv0, pv1;
      pv0.x = __expf(sb0.x - mn0); pv0.y = __expf(sb0.y - mn0);
      pv0.z = __expf(sb0.z - mn0); pv0.w = __expf(sb0.w - mn0);
      pv1.x = __expf(sb1.x - mn1); pv1.y = __expf(sb1.y - mn1);
      pv1.z = __expf(sb1.z - mn1); pv1.w = __expf(sb1.w - mn1);
      *(float4*)&p_s[2 * g][kjg * 4] = pv0;
      *(float4*)&p_s[2 * g + 1][kjg * 4] = pv1;
      psum[2 * g][kjg] = pv0.x + pv0.y + pv0.z + pv0.w;
      psum[2 * g + 1][kjg] = pv1.x + pv1.y + pv1.z + pv1.w;
      const float a0 = al_s[2 * g], a1 = al_s[2 * g + 1];
      o0.x *= a0; o0.y *= a0; o0.z *= a0; o0.w *= a0;
      o1.x *= a1; o1.y *= a1; o1.z *= a1; o1.w *= a1;
    }
    __syncthreads();
    if (t < 32) {
      float ssum = 0.f;
#pragma unroll
      for (int j = 0; j < 16; ++j) ssum += psum[t][j];
      l_s[t] = l_s[t] * al_s[t] + ssum;
    }
#pragma unroll 8
    for (int kj = 0; kj < 64; ++kj) {
      const float4 v4 = *(const float4*)&V_s[kj][kjg * 4];
      const float pa = p_s[2 * g][kj], pb = p_s[2 * g + 1][kj];
      o0.x += pa * v4.x; o0.y += pa * v4.y; o0.z += pa * v4.z; o0.w += pa * v4.w;
      o1.x += pb * v4.x; o1.y += pb * v4.y; o1.z += pb * v4.z; o1.w += pb * v4.w;
    }
  }
  __syncthreads();
  {
    const float inv0 = 1.f / l_s[2 * g];
    const float inv1 = 1.f / l_s[2 * g + 1];
    unsigned short* po0 = out + (size_t)(l0 + 2 * g) * CDIM + n * HDIM + kjg * 4;
    unsigned short* po1 = out + (size_t)(l0 + 2 * g + 1) * CDIM + n * HDIM + kjg * 4;
    po0[0] = f2b(o0.x * inv0); po0[1] = f2b(o0.y * inv0);
    po0[2] = f2b(o0.z * inv0); po0[3] = f2b(o0.w * inv0);
    po1[0] = f2b(o1.x * inv1); po1[1] = f2b(o1.y * inv1);
    po1[2] = f2b(o1.z * inv1); po1[3] = f2b(o1.w * inv1);
  }
}

// ---------------- launch ----------------
extern "C" void kernel_launch(void* const* d_in, const int* in_sizes, int n_in,
                              void* d_out, int out_size, void* d_ws, size_t ws_size,
                              hipStream_t stream) {
  const float* x     = (const float*)d_in[0];
  const float* ln1w  = (const float*)d_in[1];
  const float* ln1b  = (const float*)d_in[2];
  const float* qkvw  = (const float*)d_in[3];
  const float* qkvb  = (const float*)d_in[4];
  const float* relh  = (const float*)d_in[5];
  const float* relw  = (const float*)d_in[6];
  const float* projw = (const float*)d_in[7];
  const float* projb = (const float*)d_in[8];
  const float* ln2w  = (const float*)d_in[9];
  const float* ln2b  = (const float*)d_in[10];
  const float* fc1w  = (const float*)d_in[11];
  const float* fc1b  = (const float*)d_in[12];
  const float* fc2w  = (const float*)d_in[13];
  const float* fc2b  = (const float*)d_in[14];
  float* out = (float*)d_out;
  float* ws = (float*)d_ws;

  // fp32 regions
  float* qkv = ws;                            // L*3C = 5,308,416 f32
  float* x1  = qkv + (size_t)LTOK * 3 * CDIM; // L*C
  float* cs  = x1 + (size_t)LTOK * CDIM;      // L*32
  float* sn  = cs + (size_t)LTOK * 32;        // L*32
  // bf16 regions
  unsigned short* h_bf    = (unsigned short*)(sn + (size_t)LTOK * 32);
  unsigned short* attn_bf = h_bf + (size_t)LTOK * CDIM;
  unsigned short* wq      = attn_bf + (size_t)LTOK * CDIM;
  unsigned short* wproj   = wq + (size_t)3 * CDIM * CDIM;
  unsigned short* wfc1    = wproj + (size_t)CDIM * CDIM;
  unsigned short* wfc2    = wfc1 + (size_t)4 * CDIM * CDIM;
  unsigned short* m1_bf   = (unsigned short*)qkv;  // overlay: qkv dead after attn

  // 0. weight conversions
  f2b_kernel<<<(3 * CDIM * CDIM / 8 + 255) / 256, 256, 0, stream>>>(qkvw, wq, 3 * CDIM * CDIM);
  f2b_kernel<<<(CDIM * CDIM / 8 + 255) / 256, 256, 0, stream>>>(projw, wproj, CDIM * CDIM);
  f2b_kernel<<<(4 * CDIM * CDIM / 8 + 255) / 256, 256, 0, stream>>>(fc1w, wfc1, 4 * CDIM * CDIM);
  f2b_kernel<<<(4 * CDIM * CDIM / 8 + 255) / 256, 256, 0, stream>>>(fc2w, wfc2, 4 * CDIM * CDIM);
  // 1. LN1 -> bf16
  ln_kernel<<<LTOK, 256, 0, stream>>>(x, ln1w, ln1b, h_bf);
  // 2. qkv = h @ qkv_w^T + b  (fp32 out)
  mfma_gemm<false, false, false><<<dim3(18, 18), 256, 0, stream>>>(
      h_bf, wq, qkvb, nullptr, qkv, LTOK, 3 * CDIM, CDIM);
  // 3. RoPE
  rope_cs_kernel<<<288, 256, 0, stream>>>(cs, sn);
  rope_apply_kernel<<<6912, 256, 0, stream>>>(qkv, cs, sn);
  // 4. attention -> bf16
  attn_kernel<<<dim3(72, 12), 256, 0, stream>>>(qkv, relh, relw, attn_bf);
  // 5. x1 = x + attn @ proj_w^T + b  (fp32 out)
  mfma_gemm<false, true, false><<<dim3(6, 18), 256, 0, stream>>>(
      attn_bf, wproj, projb, x, x1, LTOK, CDIM, CDIM);
  // 6. LN2 -> bf16
  ln_kernel<<<LTOK, 256, 0, stream>>>(x1, ln2w, ln2b, h_bf);
  // 7. m1 = gelu(h @ fc1_w^T + b)  (bf16 out)
  mfma_gemm<true, false, true><<<dim3(24, 18), 256, 0, stream>>>(
      h_bf, wfc1, fc1b, nullptr, m1_bf, LTOK, 4 * CDIM, CDIM);
  // 8. out = x1 + m1 @ fc2_w^T + b  (fp32 out)
  mfma_gemm<false, true, false><<<dim3(6, 18), 256, 0, stream>>>(
      m1_bf, wfc2, fc2b, x1, out, LTOK, CDIM, 4 * CDIM);
}

// Round 4
// 296.977 us; speedup vs baseline: 4.7193x; 2.7605x over previous
//
#include <hip/hip_runtime.h>
#include <math.h>

#define LTOK 2304
#define CDIM 768
#define NHEAD 12
#define HDIM 64
#define HS 48

static constexpr float ATT_SCALE = 0.125f;  // 64^-0.5

typedef short s16x8 __attribute__((ext_vector_type(8)));   // 8 bf16 bits (4 VGPRs)
typedef float f32x4 __attribute__((ext_vector_type(4)));

__device__ __forceinline__ unsigned short f2b(float f) {
  __bf16 b = (__bf16)f;   // RNE
  return __builtin_bit_cast(unsigned short, b);
}
__device__ __forceinline__ float b2f(unsigned short u) {
  unsigned int x = ((unsigned int)u) << 16;
  return __builtin_bit_cast(float, x);
}

__device__ __forceinline__ void gld_lds16(void* lds, const void* g) {
  __builtin_amdgcn_global_load_lds(
      (const __attribute__((address_space(1))) unsigned int*)g,
      (__attribute__((address_space(3))) unsigned int*)lds, 16, 0, 0);
}

// ---------------- fp32 -> bf16 convert (n % 8 == 0) ----------------
__global__ __launch_bounds__(256) void f2b_kernel(const float* __restrict__ in,
                                                  unsigned short* __restrict__ out, int n) {
  const int i = (blockIdx.x * 256 + threadIdx.x) * 8;
  if (i + 8 > n) return;
  float4 v0 = *(const float4*)(in + i);
  float4 v1 = *(const float4*)(in + i + 4);
  alignas(16) unsigned short o[8] = {f2b(v0.x), f2b(v0.y), f2b(v0.z), f2b(v0.w),
                                     f2b(v1.x), f2b(v1.y), f2b(v1.z), f2b(v1.w)};
  *(uint4*)(out + i) = *(const uint4*)o;
}

// ---------------- LayerNorm: fp32 in, bf16 out ----------------
__global__ __launch_bounds__(256) void ln_kernel(const float* __restrict__ x,
                                                 const float* __restrict__ w,
                                                 const float* __restrict__ b,
                                                 unsigned short* __restrict__ out) {
  const int row = blockIdx.x;
  const int t = threadIdx.x;
  const float* xr = x + (size_t)row * CDIM;
  float v0 = xr[t], v1 = xr[t + 256], v2 = xr[t + 512];
  float s = v0 + v1 + v2;
  float ss = v0 * v0 + v1 * v1 + v2 * v2;
#pragma unroll
  for (int off = 32; off > 0; off >>= 1) {
    s += __shfl_down(s, off, 64);
    ss += __shfl_down(ss, off, 64);
  }
  __shared__ float rs[4], rss[4];
  if ((t & 63) == 0) { rs[t >> 6] = s; rss[t >> 6] = ss; }
  __syncthreads();
  float S = rs[0] + rs[1] + rs[2] + rs[3];
  float SS = rss[0] + rss[1] + rss[2] + rss[3];
  const float inv_c = 1.0f / (float)CDIM;
  float mu = S * inv_c;
  float var = SS * inv_c - mu * mu;
  float inv = rsqrtf(var + 1e-5f);
  unsigned short* orow = out + (size_t)row * CDIM;
  orow[t]       = f2b((v0 - mu) * inv * w[t]       + b[t]);
  orow[t + 256] = f2b((v1 - mu) * inv * w[t + 256] + b[t + 256]);
  orow[t + 512] = f2b((v2 - mu) * inv * w[t + 512] + b[t + 512]);
}

// ---------------- bf16 MFMA GEMM (m97 structure) ----------------
template <bool GELU, bool RES, bool OUTBF>
__global__ __launch_bounds__(256) void mfma_gemm(const unsigned short* __restrict__ A,
                                                 const unsigned short* __restrict__ B,
                                                 const float* __restrict__ bias,
                                                 const float* __restrict__ res,
                                                 void* __restrict__ Cout,
                                                 int M, int N, int K) {
  __shared__ unsigned short As[128 * 32];
  __shared__ unsigned short Bs[128 * 32];
  const int t = threadIdx.x;
  const int lane = t & 63;
  const int w = t >> 6;
  const int wm = w >> 1, wn = w & 1;
  const int bm = blockIdx.y * 128, bn = blockIdx.x * 128;

  f32x4 acc[4][4] = {};

  const int c0 = 2 * w, c1 = 2 * w + 1;
  const int srow = lane >> 2;
  const int skof = (lane & 3) * 8;
  const unsigned short* Abase = A + (size_t)bm * K + skof;
  const unsigned short* Bbase = B + (size_t)bn * K + skof;
  const int lr = lane & 15, lk = (lane >> 4) * 8, lg = lane >> 4;

  for (int k0 = 0; k0 < K; k0 += 32) {
    gld_lds16(As + c0 * 512, Abase + (size_t)(c0 * 16 + srow) * K + k0);
    gld_lds16(As + c1 * 512, Abase + (size_t)(c1 * 16 + srow) * K + k0);
    gld_lds16(Bs + c0 * 512, Bbase + (size_t)(c0 * 16 + srow) * K + k0);
    gld_lds16(Bs + c1 * 512, Bbase + (size_t)(c1 * 16 + srow) * K + k0);
    __syncthreads();
    s16x8 a[4], b[4];
#pragma unroll
    for (int m = 0; m < 4; ++m)
      a[m] = *(const s16x8*)&As[(wm * 64 + m * 16 + lr) * 32 + lk];
#pragma unroll
    for (int n = 0; n < 4; ++n)
      b[n] = *(const s16x8*)&Bs[(wn * 64 + n * 16 + lr) * 32 + lk];
#pragma unroll
    for (int m = 0; m < 4; ++m)
#pragma unroll
      for (int n = 0; n < 4; ++n)
        acc[m][n] = __builtin_amdgcn_mfma_f32_16x16x32_bf16(a[m], b[n], acc[m][n], 0, 0, 0);
    __syncthreads();
  }

#pragma unroll
  for (int n = 0; n < 4; ++n) {
    const int col = bn + wn * 64 + n * 16 + lr;
    const float bc = bias[col];
#pragma unroll
    for (int m = 0; m < 4; ++m) {
#pragma unroll
      for (int j = 0; j < 4; ++j) {
        const int row = bm + wm * 64 + m * 16 + lg * 4 + j;
        float v = acc[m][n][j] + bc;
        if (GELU) v = 0.5f * v * (1.0f + erff(v * 0.70710678118654752f));
        if (RES) v += res[(size_t)row * N + col];
        if (OUTBF) ((unsigned short*)Cout)[(size_t)row * N + col] = f2b(v);
        else       ((float*)Cout)[(size_t)row * N + col] = v;
      }
    }
  }
}

// ---------------- RoPE cos/sin tables: [L][32] ----------------
__global__ __launch_bounds__(256) void rope_cs_kernel(float* __restrict__ cs,
                                                      float* __restrict__ sn) {
  const int idx = blockIdx.x * 256 + threadIdx.x;  // < 2304*32
  const int l = idx >> 5;
  const int i = idx & 31;
  const int j = i & 15;
  const float f = __expf(-(float)j * 0.57564627324851142f);
  const float coord = (i < 16) ? (float)(l % HS) : (float)(l / HS);
  const float ang = coord * f;
  cs[idx] = cosf(ang);
  sn[idx] = sinf(ang);
}

// ---------------- prep: fp32 qkv -> Qb,Kb [NH][L][64] (RoPE) + Vb [NH][64][L] -------
// grid (36, 12), 256 threads
__global__ __launch_bounds__(256) void prep_kernel(const float* __restrict__ qkv,
                                                   const float* __restrict__ cs,
                                                   const float* __restrict__ sn,
                                                   unsigned short* __restrict__ Qb,
                                                   unsigned short* __restrict__ Kb,
                                                   unsigned short* __restrict__ Vb) {
  const int t = threadIdx.x;
  const int l0 = blockIdx.x * 64, n = blockIdx.y;
  const int r = t >> 2, c = t & 3;
  const int l = l0 + r;
  const float* base = qkv + (size_t)l * (3 * CDIM) + n * HDIM + c * 16;
#pragma unroll
  for (int pq = 0; pq < 2; ++pq) {
    const float* src = base + pq * CDIM;
    alignas(16) unsigned short o[16];
#pragma unroll
    for (int i = 0; i < 4; ++i) {
      float4 v = *(const float4*)(src + i * 4);
      const int pr = c * 8 + i * 2;
      const float c0 = cs[l * 32 + pr],     s0 = sn[l * 32 + pr];
      const float c1 = cs[l * 32 + pr + 1], s1 = sn[l * 32 + pr + 1];
      o[i * 4 + 0] = f2b(v.x * c0 - v.y * s0);
      o[i * 4 + 1] = f2b(v.x * s0 + v.y * c0);
      o[i * 4 + 2] = f2b(v.z * c1 - v.w * s1);
      o[i * 4 + 3] = f2b(v.z * s1 + v.w * c1);
    }
    unsigned short* dst = (pq ? Kb : Qb) + ((size_t)n * LTOK + l) * HDIM + c * 16;
    *(uint4*)dst = *(const uint4*)o;
    *(uint4*)(dst + 8) = *(const uint4*)(o + 8);
  }
  // V transpose: thread handles col d = t>>2, rows rc..rc+15
  {
    const int d = t >> 2, rc = (t & 3) * 16;
    alignas(16) unsigned short o[16];
#pragma unroll
    for (int i = 0; i < 16; ++i)
      o[i] = f2b(qkv[(size_t)(l0 + rc + i) * (3 * CDIM) + 2 * CDIM + n * HDIM + d]);
    unsigned short* dst = Vb + ((size_t)n * HDIM + d) * LTOK + l0 + rc;
    *(uint4*)dst = *(const uint4*)o;
    *(uint4*)(dst + 8) = *(const uint4*)(o + 8);
  }
}

// ---------------- MFMA flash attention, KVB=48 ----------------
// grid (36, 12), 256 threads = 4 waves x 16 q-rows
__global__ __launch_bounds__(256) void attn_mfma(const unsigned short* __restrict__ Qb,
                                                 const unsigned short* __restrict__ Kb,
                                                 const unsigned short* __restrict__ Vb,
                                                 const float* __restrict__ relh,
                                                 const float* __restrict__ relw,
                                                 unsigned short* __restrict__ out) {
  __shared__ unsigned short K_lds[48 * 64];        // [key][d], 128B rows, chunk-XOR swizzled
  __shared__ unsigned short Vt_lds[64 * 48 + 16];  // [d][key], 96B rows + zero tail
  __shared__ unsigned short Q_s[64 * 72];          // padded rows
  __shared__ float bh_t[48][64];                   // [kt][q]
  __shared__ unsigned short P_lds[4][16 * 72];     // per-wave [q][key(64)], stride 72

  const int t = threadIdx.x;
  const int lane = t & 63, w = t >> 6;
  const int p = lane & 15, g = lane >> 4;
  const int l0 = blockIdx.x * 64, n = blockIdx.y;

  // stage Q tile into padded Q_s
  {
    const int r = t >> 2, c = t & 3;
    const unsigned short* src = Qb + ((size_t)n * LTOK + l0 + r) * HDIM + c * 16;
    uint4 v0 = *(const uint4*)src;
    uint4 v1 = *(const uint4*)(src + 8);
    *(uint4*)&Q_s[r * 72 + c * 16] = v0;
    *(uint4*)&Q_s[r * 72 + c * 16 + 8] = v1;
  }
  if (t < 16) Vt_lds[64 * 48 + t] = 0;
  __syncthreads();

  // Q B-frags (lane's q-row = w*16+p)
  const s16x8 qf0 = *(const s16x8*)&Q_s[(w * 16 + p) * 72 + g * 8];
  const s16x8 qf1 = *(const s16x8*)&Q_s[(w * 16 + p) * 72 + 32 + g * 8];

  // bh_t[kt][r]: r = lane, kt = w + 4i
  const int qh_lane = (l0 + lane) / 48;
#pragma unroll
  for (int i = 0; i < 12; ++i) {
    const int kt = w + 4 * i;
    const float* rrow = relh + (size_t)(qh_lane - kt + 47) * HDIM;
    float acc = 0.f;
#pragma unroll
    for (int c8 = 0; c8 < 8; ++c8) {
      s16x8 qv = *(const s16x8*)&Q_s[lane * 72 + c8 * 8];
      float4 ra = *(const float4*)&rrow[c8 * 8];
      float4 rb = *(const float4*)&rrow[c8 * 8 + 4];
      acc += b2f((unsigned short)qv[0]) * ra.x + b2f((unsigned short)qv[1]) * ra.y +
             b2f((unsigned short)qv[2]) * ra.z + b2f((unsigned short)qv[3]) * ra.w +
             b2f((unsigned short)qv[4]) * rb.x + b2f((unsigned short)qv[5]) * rb.y +
             b2f((unsigned short)qv[6]) * rb.z + b2f((unsigned short)qv[7]) * rb.w;
    }
    bh_t[kt][lane] = acc;
  }

  // bwreg[mb*4+jj] = bw for key j = 16mb + 4g + jj (tile-local, tile-independent)
  float bwreg[12];
  {
    const int qrow = w * 16 + p;
    const int qw_lane = (l0 + qrow) % 48;
#pragma unroll
    for (int mb = 0; mb < 3; ++mb)
#pragma unroll
      for (int jj = 0; jj < 4; ++jj) {
        const int j = 16 * mb + 4 * g + jj;
        const float* rrow = relw + (size_t)(qw_lane - j + 47) * HDIM;
        float acc = 0.f;
#pragma unroll
        for (int c8 = 0; c8 < 8; ++c8) {
          s16x8 qv = *(const s16x8*)&Q_s[qrow * 72 + c8 * 8];
          float4 ra = *(const float4*)&rrow[c8 * 8];
          float4 rb = *(const float4*)&rrow[c8 * 8 + 4];
          acc += b2f((unsigned short)qv[0]) * ra.x + b2f((unsigned short)qv[1]) * ra.y +
                 b2f((unsigned short)qv[2]) * ra.z + b2f((unsigned short)qv[3]) * ra.w +
                 b2f((unsigned short)qv[4]) * rb.x + b2f((unsigned short)qv[5]) * rb.y +
                 b2f((unsigned short)qv[6]) * rb.z + b2f((unsigned short)qv[7]) * rb.w;
        }
        bwreg[mb * 4 + jj] = acc;
      }
  }

  float m = -3e38f, lsum = 0.f;
  f32x4 accO[4] = {};
  const int sw0 = g ^ (p & 7);        // swizzled d-chunk for k=0..31
  const int sw1 = (g + 4) ^ (p & 7);  // k=32..63

  for (int kt = 0; kt < 48; ++kt) {
    // --- stage K (6 x 1KB chunks; linear LDS dest, XOR-swizzled global source) ---
    {
      const int rowb = lane >> 3;
      const int srcc = (lane & 7) ^ rowb;
      gld_lds16(K_lds + w * 512,
                Kb + ((size_t)n * LTOK + kt * 48 + w * 8 + rowb) * HDIM + srcc * 8);
      if (w < 2) {
        const int c = 4 + w;
        gld_lds16(K_lds + c * 512,
                  Kb + ((size_t)n * LTOK + kt * 48 + c * 8 + rowb) * HDIM + srcc * 8);
      }
      // --- stage Vt (6 x 1KB chunks, 16B/lane; 96B rows, 96%16==0 so spans stay in-row) ---
      {
        const int Bb = w * 1024 + lane * 16;
        const int vr = Bb / 96, vc = (Bb % 96) >> 1;
        gld_lds16(Vt_lds + w * 512,
                  Vb + ((size_t)n * HDIM + vr) * LTOK + kt * 48 + vc);
      }
      if (w >= 2) {
        const int c = 2 + w;  // chunks 4,5
        const int Bb = c * 1024 + lane * 16;
        const int vr = Bb / 96, vc = (Bb % 96) >> 1;
        gld_lds16(Vt_lds + c * 512,
                  Vb + ((size_t)n * HDIM + vr) * LTOK + kt * 48 + vc);
      }
    }
    __syncthreads();

    // --- S^T = K · Q^T : D[key][q], col=lane&15=q, row=4g+jj=key-in-16 ---
    f32x4 st[3] = {};
#pragma unroll
    for (int mb = 0; mb < 3; ++mb) {
      const int krow = (16 * mb + p) * 64;
      s16x8 kf0 = *(const s16x8*)&K_lds[krow + sw0 * 8];
      s16x8 kf1 = *(const s16x8*)&K_lds[krow + sw1 * 8];
      st[mb] = __builtin_amdgcn_mfma_f32_16x16x32_bf16(kf0, qf0, st[mb], 0, 0, 0);
      st[mb] = __builtin_amdgcn_mfma_f32_16x16x32_bf16(kf1, qf1, st[mb], 0, 0, 0);
    }

    // --- bias + online softmax (per lane: q-row = w*16+p, 12 keys) ---
    const float bhv = bh_t[kt][w * 16 + p];
    float sv[12];
#pragma unroll
    for (int mb = 0; mb < 3; ++mb)
#pragma unroll
      for (int jj = 0; jj < 4; ++jj)
        sv[mb * 4 + jj] = st[mb][jj] * ATT_SCALE + bhv + bwreg[mb * 4 + jj];
    float tm = sv[0];
#pragma unroll
    for (int i = 1; i < 12; ++i) tm = fmaxf(tm, sv[i]);
    tm = fmaxf(tm, __shfl_xor(tm, 16, 64));
    tm = fmaxf(tm, __shfl_xor(tm, 32, 64));
    const float mn = fmaxf(m, tm);
    const float alpha = __expf(m - mn);
    m = mn;
    float pv[12], ps = 0.f;
#pragma unroll
    for (int i = 0; i < 12; ++i) { pv[i] = __expf(sv[i] - mn); ps += pv[i]; }
    ps += __shfl_xor(ps, 16, 64);
    ps += __shfl_xor(ps, 32, 64);
    lsum = lsum * alpha + ps;
#pragma unroll
    for (int db = 0; db < 4; ++db) accO[db] *= alpha;

    // --- P -> bf16 -> P_lds[w] rows (q=p), keys 16mb+4g+jj; zero-pad 48..63 ---
#pragma unroll
    for (int mb = 0; mb < 3; ++mb) {
      unsigned int lo = (unsigned int)f2b(pv[mb * 4 + 0]) | ((unsigned int)f2b(pv[mb * 4 + 1]) << 16);
      unsigned int hi = (unsigned int)f2b(pv[mb * 4 + 2]) | ((unsigned int)f2b(pv[mb * 4 + 3]) << 16);
      uint2 val = {lo, hi};
      *(uint2*)&P_lds[w][p * 72 + 16 * mb + 4 * g] = val;
    }
    {
      uint2 z = {0u, 0u};
      *(uint2*)&P_lds[w][p * 72 + 48 + 4 * g] = z;
    }

    // --- PV: O^T[d][q] += Vt · P^T ---
    const s16x8 pf0 = *(const s16x8*)&P_lds[w][p * 72 + g * 8];
    const s16x8 pf1 = *(const s16x8*)&P_lds[w][p * 72 + 32 + g * 8];
#pragma unroll
    for (int db = 0; db < 4; ++db) {
      const int vrow = (16 * db + p) * 48;
      s16x8 vf0 = *(const s16x8*)&Vt_lds[vrow + g * 8];
      s16x8 vf1 = *(const s16x8*)&Vt_lds[vrow + 32 + g * 8];
      accO[db] = __builtin_amdgcn_mfma_f32_16x16x32_bf16(vf0, pf0, accO[db], 0, 0, 0);
      accO[db] = __builtin_amdgcn_mfma_f32_16x16x32_bf16(vf1, pf1, accO[db], 0, 0, 0);
    }
    __syncthreads();
  }

  // epilogue: lane's q-row = w*16+p; accO[db][jj] = O[q][16db+4g+jj]
  const float inv = 1.0f / lsum;
  unsigned short* orow = out + (size_t)(l0 + w * 16 + p) * CDIM + n * HDIM;
#pragma unroll
  for (int db = 0; db < 4; ++db) {
    unsigned int lo = (unsigned int)f2b(accO[db][0] * inv) | ((unsigned int)f2b(accO[db][1] * inv) << 16);
    unsigned int hi = (unsigned int)f2b(accO[db][2] * inv) | ((unsigned int)f2b(accO[db][3] * inv) << 16);
    uint2 val = {lo, hi};
    *(uint2*)&orow[16 * db + 4 * g] = val;
  }
}

// ---------------- launch ----------------
extern "C" void kernel_launch(void* const* d_in, const int* in_sizes, int n_in,
                              void* d_out, int out_size, void* d_ws, size_t ws_size,
                              hipStream_t stream) {
  const float* x     = (const float*)d_in[0];
  const float* ln1w  = (const float*)d_in[1];
  const float* ln1b  = (const float*)d_in[2];
  const float* qkvw  = (const float*)d_in[3];
  const float* qkvb  = (const float*)d_in[4];
  const float* relh  = (const float*)d_in[5];
  const float* relw  = (const float*)d_in[6];
  const float* projw = (const float*)d_in[7];
  const float* projb = (const float*)d_in[8];
  const float* ln2w  = (const float*)d_in[9];
  const float* ln2b  = (const float*)d_in[10];
  const float* fc1w  = (const float*)d_in[11];
  const float* fc1b  = (const float*)d_in[12];
  const float* fc2w  = (const float*)d_in[13];
  const float* fc2b  = (const float*)d_in[14];
  float* out = (float*)d_out;
  float* ws = (float*)d_ws;

  float* qkv = ws;                             // L*3C f32
  float* x1  = qkv + (size_t)LTOK * 3 * CDIM;  // L*C f32 (overlaid by Qb/Kb before proj)
  float* cs  = x1 + (size_t)LTOK * CDIM;
  float* sn  = cs + (size_t)LTOK * 32;
  unsigned short* h_bf    = (unsigned short*)(sn + (size_t)LTOK * 32);
  unsigned short* attn_bf = h_bf + (size_t)LTOK * CDIM;
  unsigned short* wq      = attn_bf + (size_t)LTOK * CDIM;
  unsigned short* wproj   = wq + (size_t)3 * CDIM * CDIM;
  unsigned short* wfc1    = wproj + (size_t)CDIM * CDIM;
  unsigned short* wfc2    = wfc1 + (size_t)4 * CDIM * CDIM;
  unsigned short* Qb      = (unsigned short*)x1;   // 12*2304*64 (Qb+Kb fit x1 exactly)
  unsigned short* Kb      = Qb + (size_t)NHEAD * LTOK * HDIM;
  unsigned short* Vb      = wq;                    // overlay: wq dead after qkv GEMM (same size)
  unsigned short* m1_bf   = (unsigned short*)qkv;  // overlay: qkv dead after prep

  f2b_kernel<<<(3 * CDIM * CDIM / 8 + 255) / 256, 256, 0, stream>>>(qkvw, wq, 3 * CDIM * CDIM);
  f2b_kernel<<<(CDIM * CDIM / 8 + 255) / 256, 256, 0, stream>>>(projw, wproj, CDIM * CDIM);
  f2b_kernel<<<(4 * CDIM * CDIM / 8 + 255) / 256, 256, 0, stream>>>(fc1w, wfc1, 4 * CDIM * CDIM);
  f2b_kernel<<<(4 * CDIM * CDIM / 8 + 255) / 256, 256, 0, stream>>>(fc2w, wfc2, 4 * CDIM * CDIM);

  ln_kernel<<<LTOK, 256, 0, stream>>>(x, ln1w, ln1b, h_bf);
  mfma_gemm<false, false, false><<<dim3(18, 18), 256, 0, stream>>>(
      h_bf, wq, qkvb, nullptr, qkv, LTOK, 3 * CDIM, CDIM);
  rope_cs_kernel<<<288, 256, 0, stream>>>(cs, sn);
  prep_kernel<<<dim3(36, 12), 256, 0, stream>>>(qkv, cs, sn, Qb, Kb, Vb);
  attn_mfma<<<dim3(36, 12), 256, 0, stream>>>(Qb, Kb, Vb, relh, relw, attn_bf);
  mfma_gemm<false, true, false><<<dim3(6, 18), 256, 0, stream>>>(
      attn_bf, wproj, projb, x, x1, LTOK, CDIM, CDIM);
  ln_kernel<<<LTOK, 256, 0, stream>>>(x1, ln2w, ln2b, h_bf);
  mfma_gemm<true, false, true><<<dim3(24, 18), 256, 0, stream>>>(
      h_bf, wfc1, fc1b, nullptr, m1_bf, LTOK, 4 * CDIM, CDIM);
  mfma_gemm<false, true, false><<<dim3(6, 18), 256, 0, stream>>>(
      m1_bf, wfc2, fc2b, x1, out, LTOK, CDIM, 4 * CDIM);
}